// Round 9
// baseline (47.326 us; speedup 1.0000x reference)
//
#include <hip/hip_runtime.h>
#include <hip/hip_fp16.h>

typedef unsigned short ushort_t;
typedef unsigned int uint_t;

#define HH 128
#define WW 128
#define CIN 128
#define COUT 128
#define NPIX (HH * WW)          // 16384 pixels per batch
#define PIXB 256                // bytes per f16 pixel (128 ch * 2B)
#define BP 32                   // positions per block
#define LDB 136                 // B row stride elems (128 + 8 pad; 272B)
#define ASZ 4096                // A buffer elems per tap (64 o x 64 c, swizzled)
#define BSZ (BP * LDB)          // 4352
#define NTASK (9 * BP)          // 288

typedef __attribute__((ext_vector_type(8))) _Float16 f16x8;
typedef __attribute__((ext_vector_type(4))) float f32x4;

static __device__ __forceinline__ int imin(int a, int b) { return a < b ? a : b; }
static __device__ __forceinline__ int imax(int a, int b) { return a > b ? a : b; }

static __device__ __forceinline__ ushort_t f2h(float f) {
  union { __half h; ushort_t u; } x; x.h = __float2half(f); return x.u;
}

// packed f16 bilinear: r = w00*c0 + w01*c1 + w10*c2 + w11*c3 (2 channels/uint)
static __device__ __forceinline__ uint_t pk4(uint_t c0, uint_t c1, uint_t c2, uint_t c3,
                                             __half2 w00, __half2 w01,
                                             __half2 w10, __half2 w11) {
  union { uint_t u; __half2 h; } a0, a1, a2, a3, r;
  a0.u = c0; a1.u = c1; a2.u = c2; a3.u = c3;
  r.h = __hfma2(w00, a0.h, __hfma2(w01, a1.h, __hfma2(w10, a2.h, __hmul2(w11, a3.h))));
  return r.u;
}

// single-inst v_perm_b32 half-duplications
static __device__ __forceinline__ __half2 dup_lo(uint_t u) {
  union { uint_t u; __half2 h; } x;
  x.u = __builtin_amdgcn_perm(u, u, 0x05040504u);  // bytes [1,0,1,0]
  return x.h;
}
static __device__ __forceinline__ __half2 dup_hi(uint_t u) {
  union { uint_t u; __half2 h; } x;
  x.u = __builtin_amdgcn_perm(u, u, 0x07060706u);  // bytes [3,2,3,2]
  return x.h;
}

// bilinear commit: 4 corner uint4s (8 f16 ch each) + packed f16 weights -> LDS
static __device__ __forceinline__ void commit_f16(const uint4* cf, uint2 wz, ushort_t* dst) {
  __half2 w00 = dup_lo(wz.x), w01 = dup_hi(wz.x);
  __half2 w10 = dup_lo(wz.y), w11 = dup_hi(wz.y);
  uint4 r;
  r.x = pk4(cf[0].x, cf[1].x, cf[2].x, cf[3].x, w00, w01, w10, w11);
  r.y = pk4(cf[0].y, cf[1].y, cf[2].y, cf[3].y, w00, w01, w10, w11);
  r.z = pk4(cf[0].z, cf[1].z, cf[2].z, cf[3].z, w00, w01, w10, w11);
  r.w = pk4(cf[0].w, cf[1].w, cf[2].w, cf[3].w, w00, w01, w10, w11);
  *(uint4*)dst = r;
}

// K0 (unified prep): blocks [0,8192): transpose BCHW f32 -> NHWC f16;
// [8192,8336): weight -> f16 tap-major XOR-swizzled; [8336,9488): offset copy.
__global__ void prep_all(const float* __restrict__ x, uint_t* __restrict__ xtb,
                         const float* __restrict__ w, ushort_t* __restrict__ wf,
                         const float4* __restrict__ off_in, float4* __restrict__ off_out,
                         int n4) {
  int bid = blockIdx.x;
  int tid = threadIdx.x;
  if (bid < 8192) {
    __shared__ float tile[32][33];
    int b  = bid >> 11;
    int c0 = ((bid >> 9) & 3) * 32;
    int s0 = (bid & 511) * 32;
    int tx = tid & 31;
    int ty = tid >> 5;       // 0..7
    const float* inb = x + (size_t)b * CIN * NPIX;
    uint_t* outb = xtb + (size_t)b * NPIX * (CIN / 2);
#pragma unroll
    for (int i = 0; i < 4; ++i) {
      int c = c0 + ty + 8 * i;
      tile[ty + 8 * i][tx] = inb[(size_t)c * NPIX + s0 + tx];
    }
    __syncthreads();
    int s = tid >> 3;        // spatial 0..31
    int j = tid & 7;         // channel quad 0..7 -> channels c0+4j..c0+4j+3
    __half2 pa = __float22half2_rn(make_float2(tile[4 * j + 0][s], tile[4 * j + 1][s]));
    __half2 pb = __float22half2_rn(make_float2(tile[4 * j + 2][s], tile[4 * j + 3][s]));
    uint2 v;
    v.x = *(uint_t*)&pa;
    v.y = *(uint_t*)&pb;
    *(uint2*)&outb[(size_t)(s0 + s) * (CIN / 2) + (c0 >> 1) + 2 * j] = v;
  } else if (bid < 8192 + 144) {
    // dest elem for (k,o,c): k*4096 + (((o*8 + (c>>3)) ^ (o&7)) * 8 + (c&7))
    int i = (bid - 8192) * 256 + tid;
    int k = i >> 12, e = i & 4095;
    int gp = e >> 3, sub = e & 7;
    int o = gp >> 3;
    int c = (((gp & 7) ^ (o & 7)) << 3) | sub;
    wf[i] = f2h(w[(o * 64 + c) * 9 + k]);
  } else {
    int i = (bid - 8336) * 256 + tid;
    if (i < n4) off_out[i] = off_in[i];
  }
}

// K1: fused gather + MFMA. 2048 blocks x 512 thr. Tile: 128 o x 32 pos, 9 taps.
// LDS = 40704B -> 4 blocks/CU (32 waves = HW max); VGPR must stay <=64.
__global__ __launch_bounds__(512, 4)
void deform_main(const ushort_t* __restrict__ xtb, const float* __restrict__ off,
                 const ushort_t* __restrict__ wf, const float* __restrict__ bias,
                 float* __restrict__ out) {
  __shared__ __align__(16) ushort_t Alds[2 * ASZ];   // weight f16, swizzled granules
  __shared__ __align__(16) ushort_t Blds[2 * BSZ];   // val f16 [p][c]
  __shared__ __align__(16) int4  mo[NTASK];          // 4 corner byte offsets (pix*256)
  __shared__ __align__(16) uint2 mw[NTASK];          // 4 packed f16 weights

  const int n  = blockIdx.x;
  const int l  = (n & 7) * 256 + (n >> 3);           // XCD swizzle (2048%8==0)
  const int b  = l >> 9;
  const int rr = l & 511;
  const int ho = rr >> 2;
  const int wo0 = (rr & 3) << 5;

  const int tid  = threadIdx.x;
  const int wv   = tid >> 6;
  const int lane = tid & 63;
  const int r    = lane & 15;
  const int g    = lane >> 4;
  const int ob   = (wv & 3) << 5;
  const int pb   = (wv >> 2) << 4;
  const int arow = ob & 32;
  const int cb   = ob & 64;

  // ---- meta: 9 taps x 32 positions ----
  if (tid < NTASK) {
    int k = tid >> 5, p = tid & 31;
    int ky = k / 3, kx = k % 3;
    int wo = wo0 + p;
    float dy = off[((b * 18 + 2 * k) * HH + ho) * WW + wo];
    float dx = off[((b * 18 + 2 * k + 1) * HH + ho) * WW + wo];
    float py = dy + (float)(ky + ho - 1);
    float px = dx + (float)(kx + wo - 1);
    float y0f = floorf(py), x0f = floorf(px);
    float ly = py - y0f, lx = px - x0f;
    int y0 = (int)y0f, x0 = (int)x0f;
    int y1 = y0 + 1, x1 = x0 + 1;
    float wy0 = 1.f - ly, wx0 = 1.f - lx;
    bool vy0 = (y0 >= 0) & (y0 < HH), vy1 = (y1 >= 0) & (y1 < HH);
    bool vx0 = (x0 >= 0) & (x0 < WW), vx1 = (x1 >= 0) & (x1 < WW);
    int y0c = imin(imax(y0, 0), HH - 1), y1c = imin(imax(y1, 0), HH - 1);
    int x0c = imin(imax(x0, 0), WW - 1), x1c = imin(imax(x1, 0), WW - 1);
    float f00 = (vy0 && vx0) ? wy0 * wx0 : 0.f;
    float f01 = (vy0 && vx1) ? wy0 * lx  : 0.f;
    float f10 = (vy1 && vx0) ? ly  * wx0 : 0.f;
    float f11 = (vy1 && vx1) ? ly  * lx  : 0.f;
    int4 o4;
    o4.x = (y0c * WW + x0c) * PIXB;
    o4.y = (y0c * WW + x1c) * PIXB;
    o4.z = (y1c * WW + x0c) * PIXB;
    o4.w = (y1c * WW + x1c) * PIXB;
    mo[tid] = o4;
    mw[tid] = make_uint2((uint_t)f2h(f00) | ((uint_t)f2h(f01) << 16),
                         (uint_t)f2h(f10) | ((uint_t)f2h(f11) << 16));
  }

  // gather mapping: one task (4 corners, 8 ch) per thread per tap.
  // BLOCK-UNIFORM base + 32-bit voffset -> saddr-form global_load_dwordx4.
  const int qb = (tid & 15) << 4;     // channel-octet byte offset within pixel
  const int p0 = tid >> 4;            // position 0..31
  const char* xbase = (const char*)xtb + (size_t)b * NPIX * PIXB;  // uniform

  // A gload mapping: thread copies 16B; pre-swizzled source is linear
  const char* asrc = (const char*)wf + tid * 16;
  char* adst0 = (char*)Alds + wv * 1024;

  uint4 cf[4];      // in-flight gather (one task)
  uint2 wz;

  __syncthreads();  // meta ready

  // ---- prologue: tap 0 into buffer 0 ----
  {
    __builtin_amdgcn_global_load_lds(
        (const __attribute__((address_space(1))) uint_t*)asrc,
        (__attribute__((address_space(3))) uint_t*)adst0, 16, 0, 0);
    int4 o4 = mo[p0];
    wz = mw[p0];
    cf[0] = *(const uint4*)(xbase + (o4.x + qb));
    cf[1] = *(const uint4*)(xbase + (o4.y + qb));
    cf[2] = *(const uint4*)(xbase + (o4.z + qb));
    cf[3] = *(const uint4*)(xbase + (o4.w + qb));
    commit_f16(cf, wz, &Blds[p0 * LDB + qb / 2]);
  }
  __syncthreads();

  f32x4 acc0 = {0.f, 0.f, 0.f, 0.f};
  f32x4 acc1 = {0.f, 0.f, 0.f, 0.f};

  const int o0r = arow + r, o1r = arow + 16 + r;
  const int g0base = (o0r << 3) + g, g0m = o0r & 7;
  const int g1base = (o1r << 3) + g, g1m = o1r & 7;

  // ---- main loop: 9 taps, double-buffered, 1-tap lookahead ----
  for (int t = 0; t < 9; ++t) {
    const int bs = t & 1, ns = bs ^ 1;

    if (t < 8) {
      __builtin_amdgcn_global_load_lds(
          (const __attribute__((address_space(1))) uint_t*)(asrc + (t + 1) * 8192),
          (__attribute__((address_space(3))) uint_t*)(adst0 + ns * 8192), 16, 0, 0);
      int4 o4 = mo[(t + 1) * 32 + p0];
      wz = mw[(t + 1) * 32 + p0];
      cf[0] = *(const uint4*)(xbase + (o4.x + qb));
      cf[1] = *(const uint4*)(xbase + (o4.y + qb));
      cf[2] = *(const uint4*)(xbase + (o4.z + qb));
      cf[3] = *(const uint4*)(xbase + (o4.w + qb));
    }
    __builtin_amdgcn_sched_barrier(0);   // keep issue-block above GEMM (no sinking)

    // GEMM on current buffer: K=64, 2 steps of 32
    {
      const ushort_t* Ab = &Alds[bs * ASZ];
      const ushort_t* Bb = &Blds[bs * BSZ];
#pragma unroll
      for (int ks = 0; ks < 2; ++ks) {
        int kk = ks * 32 + g * 8;
        f16x8 a0 = *(const f16x8*)&Ab[(((g0base + (ks << 2)) ^ g0m) << 3)];
        f16x8 a1 = *(const f16x8*)&Ab[(((g1base + (ks << 2)) ^ g1m) << 3)];
        f16x8 bbf = *(const f16x8*)&Bb[(pb + r) * LDB + cb + kk];
        acc0 = __builtin_amdgcn_mfma_f32_16x16x32_f16(a0, bbf, acc0, 0, 0, 0);
        acc1 = __builtin_amdgcn_mfma_f32_16x16x32_f16(a1, bbf, acc1, 0, 0, 0);
      }
    }

    // commit tap t+1 into the other buffer
    if (t < 8) {
      commit_f16(cf, wz, &Blds[ns * BSZ + p0 * LDB + qb / 2]);
    }
    __syncthreads();
  }

  // ---- epilogue: D col = lane&15 (pos), row = 4*(lane>>4)+reg (o) ----
  int wo = wo0 + pb + r;
#pragma unroll
  for (int qq = 0; qq < 4; ++qq) {
    int o0 = ob + 4 * g + qq;
    int o1 = o0 + 16;
    out[((size_t)(b * COUT + o0) * HH + ho) * WW + wo] = acc0[qq] + bias[o0 & 63];
    out[((size_t)(b * COUT + o1) * HH + ho) * WW + wo] = acc1[qq] + bias[o1 & 63];
  }
}

extern "C" void kernel_launch(void* const* d_in, const int* in_sizes, int n_in,
                              void* d_out, int out_size, void* d_ws, size_t ws_size,
                              hipStream_t stream) {
  const float* x      = (const float*)d_in[0];
  const float* offset = (const float*)d_in[1];
  const float* weight = (const float*)d_in[2];
  const float* bias   = (const float*)d_in[3];
  float* out = (float*)d_out;

  const size_t xt_elems = (size_t)4 * NPIX * CIN;           // 8,388,608 f16
  ushort_t* xtb = (ushort_t*)d_ws;
  ushort_t* wf  = (ushort_t*)((char*)d_ws + xt_elems * sizeof(ushort_t));

  const int off_elems = 4 * 18 * NPIX;
  const int n4 = off_elems / 4;                             // 294912 float4s

  prep_all<<<8192 + 144 + 1152, 256, 0, stream>>>(
      x, (uint_t*)xtb, weight, wf, (const float4*)offset,
      (float4*)(out + (size_t)4 * COUT * NPIX), n4);

  deform_main<<<2048, 512, 0, stream>>>(xtb, offset, wf, bias, out);
}

// Round 10
// 46.692 us; speedup vs baseline: 1.0136x; 1.0136x over previous
//
#include <hip/hip_runtime.h>
#include <hip/hip_fp16.h>

typedef unsigned short ushort_t;
typedef unsigned int uint_t;

#define HH 128
#define WW 128
#define CIN 128
#define COUT 128
#define NPIX (HH * WW)          // 16384 pixels per batch
#define PIXB 256                // bytes per f16 pixel (128 ch * 2B)
#define BP 32                   // positions per block (4 rows x 8 cols)
#define LDB 136                 // B row stride elems (128 + 8 pad; 272B)
#define ASZ 4096                // A buffer elems per tap (64 o x 64 c, swizzled)
#define BSZ (BP * LDB)          // 4352
#define NTASK (9 * BP)          // 288

typedef __attribute__((ext_vector_type(8))) _Float16 f16x8;
typedef __attribute__((ext_vector_type(4))) float f32x4;

static __device__ __forceinline__ int imin(int a, int b) { return a < b ? a : b; }
static __device__ __forceinline__ int imax(int a, int b) { return a > b ? a : b; }

static __device__ __forceinline__ ushort_t f2h(float f) {
  union { __half h; ushort_t u; } x; x.h = __float2half(f); return x.u;
}

// packed f16 bilinear: r = w00*c0 + w01*c1 + w10*c2 + w11*c3 (2 channels/uint)
static __device__ __forceinline__ uint_t pk4(uint_t c0, uint_t c1, uint_t c2, uint_t c3,
                                             __half2 w00, __half2 w01,
                                             __half2 w10, __half2 w11) {
  union { uint_t u; __half2 h; } a0, a1, a2, a3, r;
  a0.u = c0; a1.u = c1; a2.u = c2; a3.u = c3;
  r.h = __hfma2(w00, a0.h, __hfma2(w01, a1.h, __hfma2(w10, a2.h, __hmul2(w11, a3.h))));
  return r.u;
}

// single-inst v_perm_b32 half-duplications
static __device__ __forceinline__ __half2 dup_lo(uint_t u) {
  union { uint_t u; __half2 h; } x;
  x.u = __builtin_amdgcn_perm(u, u, 0x05040504u);  // bytes [1,0,1,0]
  return x.h;
}
static __device__ __forceinline__ __half2 dup_hi(uint_t u) {
  union { uint_t u; __half2 h; } x;
  x.u = __builtin_amdgcn_perm(u, u, 0x07060706u);  // bytes [3,2,3,2]
  return x.h;
}

// bilinear commit: 4 corner uint4s (8 f16 ch each) + packed f16 weights -> LDS
static __device__ __forceinline__ void commit_f16(const uint4* cf, uint2 wz, ushort_t* dst) {
  __half2 w00 = dup_lo(wz.x), w01 = dup_hi(wz.x);
  __half2 w10 = dup_lo(wz.y), w11 = dup_hi(wz.y);
  uint4 r;
  r.x = pk4(cf[0].x, cf[1].x, cf[2].x, cf[3].x, w00, w01, w10, w11);
  r.y = pk4(cf[0].y, cf[1].y, cf[2].y, cf[3].y, w00, w01, w10, w11);
  r.z = pk4(cf[0].z, cf[1].z, cf[2].z, cf[3].z, w00, w01, w10, w11);
  r.w = pk4(cf[0].w, cf[1].w, cf[2].w, cf[3].w, w00, w01, w10, w11);
  *(uint4*)dst = r;
}

// K0 (unified prep): blocks [0,8192): transpose BCHW f32 -> NHWC f16;
// [8192,8336): weight -> f16 tap-major XOR-swizzled; [8336,9488): offset copy.
__global__ void prep_all(const float* __restrict__ x, uint_t* __restrict__ xtb,
                         const float* __restrict__ w, ushort_t* __restrict__ wf,
                         const float4* __restrict__ off_in, float4* __restrict__ off_out,
                         int n4) {
  int bid = blockIdx.x;
  int tid = threadIdx.x;
  if (bid < 8192) {
    __shared__ float tile[32][33];
    int b  = bid >> 11;
    int c0 = ((bid >> 9) & 3) * 32;
    int s0 = (bid & 511) * 32;
    int tx = tid & 31;
    int ty = tid >> 5;       // 0..7
    const float* inb = x + (size_t)b * CIN * NPIX;
    uint_t* outb = xtb + (size_t)b * NPIX * (CIN / 2);
#pragma unroll
    for (int i = 0; i < 4; ++i) {
      int c = c0 + ty + 8 * i;
      tile[ty + 8 * i][tx] = inb[(size_t)c * NPIX + s0 + tx];
    }
    __syncthreads();
    int s = tid >> 3;        // spatial 0..31
    int j = tid & 7;         // channel quad 0..7
    __half2 pa = __float22half2_rn(make_float2(tile[4 * j + 0][s], tile[4 * j + 1][s]));
    __half2 pb = __float22half2_rn(make_float2(tile[4 * j + 2][s], tile[4 * j + 3][s]));
    uint2 v;
    v.x = *(uint_t*)&pa;
    v.y = *(uint_t*)&pb;
    *(uint2*)&outb[(size_t)(s0 + s) * (CIN / 2) + (c0 >> 1) + 2 * j] = v;
  } else if (bid < 8192 + 144) {
    // dest elem for (k,o,c): k*4096 + (((o*8 + (c>>3)) ^ (o&7)) * 8 + (c&7))
    int i = (bid - 8192) * 256 + tid;
    int k = i >> 12, e = i & 4095;
    int gp = e >> 3, sub = e & 7;
    int o = gp >> 3;
    int c = (((gp & 7) ^ (o & 7)) << 3) | sub;
    wf[i] = f2h(w[(o * 64 + c) * 9 + k]);
  } else {
    int i = (bid - 8336) * 256 + tid;
    if (i < n4) off_out[i] = off_in[i];
  }
}

// K1: fused gather + MFMA. 2048 blocks x 512 thr.
// Tile: 128 out-ch x 32 positions arranged as 4 rows x 8 cols (L1 locality), 9 taps.
// LDS = 40704B -> 4 blocks/CU (32 waves = HW max); VGPR must stay <=64.
__global__ __launch_bounds__(512, 4)
void deform_main(const ushort_t* __restrict__ xtb, const float* __restrict__ off,
                 const ushort_t* __restrict__ wf, const float* __restrict__ bias,
                 float* __restrict__ out) {
  __shared__ __align__(16) ushort_t Alds[2 * ASZ];   // weight f16, swizzled granules
  __shared__ __align__(16) ushort_t Blds[2 * BSZ];   // val f16 [p][c]
  __shared__ __align__(16) int4  mo[NTASK];          // 4 corner byte offsets (pix*256)
  __shared__ __align__(16) uint2 mw[NTASK];          // 4 packed f16 weights

  const int n  = blockIdx.x;
  const int l  = (n & 7) * 256 + (n >> 3);           // XCD swizzle (2048%8==0)
  const int b  = l >> 9;
  const int rr = l & 511;
  const int ho0 = (rr >> 4) << 2;                    // 32 row-bands of 4
  const int wo0 = (rr & 15) << 3;                    // 16 col-tiles of 8

  const int tid  = threadIdx.x;
  const int wv   = tid >> 6;
  const int lane = tid & 63;
  const int r    = lane & 15;
  const int g    = lane >> 4;
  const int ob   = (wv & 3) << 5;
  const int pb   = (wv >> 2) << 4;
  const int arow = ob & 32;
  const int cb   = ob & 64;

  // ---- meta: 9 taps x 32 positions (pos = 4 rows x 8 cols) ----
  if (tid < NTASK) {
    int k = tid >> 5, p = tid & 31;
    int ky = k / 3, kx = k % 3;
    int wo  = wo0 + (p & 7);
    int hop = ho0 + (p >> 3);
    float dy = off[((b * 18 + 2 * k) * HH + hop) * WW + wo];
    float dx = off[((b * 18 + 2 * k + 1) * HH + hop) * WW + wo];
    float py = dy + (float)(ky + hop - 1);
    float px = dx + (float)(kx + wo - 1);
    float y0f = floorf(py), x0f = floorf(px);
    float ly = py - y0f, lx = px - x0f;
    int y0 = (int)y0f, x0 = (int)x0f;
    int y1 = y0 + 1, x1 = x0 + 1;
    float wy0 = 1.f - ly, wx0 = 1.f - lx;
    bool vy0 = (y0 >= 0) & (y0 < HH), vy1 = (y1 >= 0) & (y1 < HH);
    bool vx0 = (x0 >= 0) & (x0 < WW), vx1 = (x1 >= 0) & (x1 < WW);
    int y0c = imin(imax(y0, 0), HH - 1), y1c = imin(imax(y1, 0), HH - 1);
    int x0c = imin(imax(x0, 0), WW - 1), x1c = imin(imax(x1, 0), WW - 1);
    float f00 = (vy0 && vx0) ? wy0 * wx0 : 0.f;
    float f01 = (vy0 && vx1) ? wy0 * lx  : 0.f;
    float f10 = (vy1 && vx0) ? ly  * wx0 : 0.f;
    float f11 = (vy1 && vx1) ? ly  * lx  : 0.f;
    int4 o4;
    o4.x = (y0c * WW + x0c) * PIXB;
    o4.y = (y0c * WW + x1c) * PIXB;
    o4.z = (y1c * WW + x0c) * PIXB;
    o4.w = (y1c * WW + x1c) * PIXB;
    mo[tid] = o4;
    mw[tid] = make_uint2((uint_t)f2h(f00) | ((uint_t)f2h(f01) << 16),
                         (uint_t)f2h(f10) | ((uint_t)f2h(f11) << 16));
  }

  // gather mapping: one task (4 corners, 8 ch) per thread per tap.
  // BLOCK-UNIFORM base + 32-bit voffset -> saddr-form global_load_dwordx4.
  const int qb = (tid & 15) << 4;     // channel-octet byte offset within pixel
  const int p0 = tid >> 4;            // position 0..31
  const char* xbase = (const char*)xtb + (size_t)b * NPIX * PIXB;  // uniform

  // A gload mapping: thread copies 16B; pre-swizzled source is linear
  const char* asrc = (const char*)wf + tid * 16;
  char* adst0 = (char*)Alds + wv * 1024;

  uint4 cf[4];      // in-flight gather (one task)
  uint2 wz;

  __syncthreads();  // meta ready

  // ---- prologue: tap 0 into buffer 0 ----
  {
    __builtin_amdgcn_global_load_lds(
        (const __attribute__((address_space(1))) uint_t*)asrc,
        (__attribute__((address_space(3))) uint_t*)adst0, 16, 0, 0);
    int4 o4 = mo[p0];
    wz = mw[p0];
    cf[0] = *(const uint4*)(xbase + (o4.x + qb));
    cf[1] = *(const uint4*)(xbase + (o4.y + qb));
    cf[2] = *(const uint4*)(xbase + (o4.z + qb));
    cf[3] = *(const uint4*)(xbase + (o4.w + qb));
    commit_f16(cf, wz, &Blds[p0 * LDB + qb / 2]);
  }
  __syncthreads();

  f32x4 acc0 = {0.f, 0.f, 0.f, 0.f};
  f32x4 acc1 = {0.f, 0.f, 0.f, 0.f};

  const int o0r = arow + r, o1r = arow + 16 + r;
  const int g0base = (o0r << 3) + g, g0m = o0r & 7;
  const int g1base = (o1r << 3) + g, g1m = o1r & 7;

  // ---- main loop: 9 taps, double-buffered, 1-tap lookahead ----
  for (int t = 0; t < 9; ++t) {
    const int bs = t & 1, ns = bs ^ 1;

    if (t < 8) {
      __builtin_amdgcn_global_load_lds(
          (const __attribute__((address_space(1))) uint_t*)(asrc + (t + 1) * 8192),
          (__attribute__((address_space(3))) uint_t*)(adst0 + ns * 8192), 16, 0, 0);
      int4 o4 = mo[(t + 1) * 32 + p0];
      wz = mw[(t + 1) * 32 + p0];
      cf[0] = *(const uint4*)(xbase + (o4.x + qb));
      cf[1] = *(const uint4*)(xbase + (o4.y + qb));
      cf[2] = *(const uint4*)(xbase + (o4.z + qb));
      cf[3] = *(const uint4*)(xbase + (o4.w + qb));
    }
    __builtin_amdgcn_sched_barrier(0);   // keep issue-block above GEMM (no sinking)

    // GEMM on current buffer: K=64, 2 steps of 32
    {
      const ushort_t* Ab = &Alds[bs * ASZ];
      const ushort_t* Bb = &Blds[bs * BSZ];
#pragma unroll
      for (int ks = 0; ks < 2; ++ks) {
        int kk = ks * 32 + g * 8;
        f16x8 a0 = *(const f16x8*)&Ab[(((g0base + (ks << 2)) ^ g0m) << 3)];
        f16x8 a1 = *(const f16x8*)&Ab[(((g1base + (ks << 2)) ^ g1m) << 3)];
        f16x8 bbf = *(const f16x8*)&Bb[(pb + r) * LDB + cb + kk];
        acc0 = __builtin_amdgcn_mfma_f32_16x16x32_f16(a0, bbf, acc0, 0, 0, 0);
        acc1 = __builtin_amdgcn_mfma_f32_16x16x32_f16(a1, bbf, acc1, 0, 0, 0);
      }
    }

    // commit tap t+1 into the other buffer
    if (t < 8) {
      commit_f16(cf, wz, &Blds[ns * BSZ + p0 * LDB + qb / 2]);
    }
    __syncthreads();
  }

  // ---- epilogue: D col = lane&15 (pos), row = 4*(lane>>4)+reg (o) ----
  int p   = pb + r;
  int hop = ho0 + (p >> 3);
  int wo  = wo0 + (p & 7);
#pragma unroll
  for (int qq = 0; qq < 4; ++qq) {
    int o0 = ob + 4 * g + qq;
    int o1 = o0 + 16;
    out[((size_t)(b * COUT + o0) * HH + hop) * WW + wo] = acc0[qq] + bias[o0 & 63];
    out[((size_t)(b * COUT + o1) * HH + hop) * WW + wo] = acc1[qq] + bias[o1 & 63];
  }
}

extern "C" void kernel_launch(void* const* d_in, const int* in_sizes, int n_in,
                              void* d_out, int out_size, void* d_ws, size_t ws_size,
                              hipStream_t stream) {
  const float* x      = (const float*)d_in[0];
  const float* offset = (const float*)d_in[1];
  const float* weight = (const float*)d_in[2];
  const float* bias   = (const float*)d_in[3];
  float* out = (float*)d_out;

  const size_t xt_elems = (size_t)4 * NPIX * CIN;           // 8,388,608 f16
  ushort_t* xtb = (ushort_t*)d_ws;
  ushort_t* wf  = (ushort_t*)((char*)d_ws + xt_elems * sizeof(ushort_t));

  const int off_elems = 4 * 18 * NPIX;
  const int n4 = off_elems / 4;                             // 294912 float4s

  prep_all<<<8192 + 144 + 1152, 256, 0, stream>>>(
      x, (uint_t*)xtb, weight, wf, (const float4*)offset,
      (float4*)(out + (size_t)4 * COUT * NPIX), n4);

  deform_main<<<2048, 512, 0, stream>>>(xtb, offset, wf, bias, out);
}